// Round 1
// baseline (362.786 us; speedup 1.0000x reference)
//
#include <hip/hip_runtime.h>
#include <hip/hip_bf16.h>

#define BB 128
#define NN 1024
#define DD 2048

// ---------------- Kernel 1: q = h_t @ W_attn  ([B,D] = [B,D]@[D,D]) ----------
// grid (16 d-tiles, 16 k-splits), block 256 (16 tx x 16 ty), 8x8 reg tile.
// Each block: d-range 128, k-range 128, all 128 b. atomicAdd epilogue (q zeroed).
__global__ __launch_bounds__(256) void qgemm(const float* __restrict__ ht,
                                             const float* __restrict__ W,
                                             float* __restrict__ q) {
    const int d0 = blockIdx.x * 128;
    const int k0 = blockIdx.y * 128;
    const int t  = threadIdx.x;
    const int tx = t & 15;   // d-group: d = d0 + tx*8 + j
    const int ty = t >> 4;   // b-group: b = ty*8 + i

    __shared__ float hs[128][33];   // [b][kk] chunk of 32 k  (pad 33: conflict-free)
    __shared__ float ws[32][132];   // [kk][d] chunk          (pad 132: 16B-aligned rows)

    float acc[8][8];
#pragma unroll
    for (int i = 0; i < 8; i++)
#pragma unroll
        for (int j = 0; j < 8; j++) acc[i][j] = 0.f;

    for (int kc = 0; kc < 128; kc += 32) {
        __syncthreads();
        // stage h_t[128 b][32 k] -> hs   (coalesced along k)
#pragma unroll
        for (int i = 0; i < 16; i++) {
            int idx = i * 256 + t;
            int c = idx & 31, r = idx >> 5;
            hs[r][c] = ht[r * DD + k0 + kc + c];
        }
        // stage W[32 k][128 d] -> ws     (coalesced along d)
#pragma unroll
        for (int i = 0; i < 16; i++) {
            int idx = i * 256 + t;
            int c = idx & 127, r = idx >> 7;
            ws[r][c] = W[(size_t)(k0 + kc + r) * DD + d0 + c];
        }
        __syncthreads();
#pragma unroll
        for (int kk = 0; kk < 32; kk++) {
            float wv[8], hv[8];
#pragma unroll
            for (int j = 0; j < 8; j++) wv[j] = ws[kk][tx * 8 + j];
#pragma unroll
            for (int i = 0; i < 8; i++) hv[i] = hs[ty * 8 + i][kk];
#pragma unroll
            for (int i = 0; i < 8; i++)
#pragma unroll
                for (int j = 0; j < 8; j++) acc[i][j] += hv[i] * wv[j];
        }
    }
#pragma unroll
    for (int i = 0; i < 8; i++) {
        int b = ty * 8 + i;
#pragma unroll
        for (int j = 0; j < 8; j++)
            atomicAdd(&q[b * DD + d0 + tx * 8 + j], acc[i][j]);
    }
}

// ---------------- Kernel 2: fused scores + elementwise + context -------------
// grid (B, 8 n-chunks), block 256 = 4 waves. Wave owns 32 n-rows.
// Per row: read h[b,n,:] ONCE (8x float4/lane), dot with reg-resident q[b],
// 64-lane butterfly reduce, exp/elementwise outputs, accumulate alpha*h into
// per-lane c registers. LDS combine across 4 waves, atomicAdd into c_t.
__global__ __launch_bounds__(256) void fused(const float* __restrict__ q,
                                             const float* __restrict__ h,
                                             const float* __restrict__ pe,
                                             const float* __restrict__ pee,
                                             float* __restrict__ out) {
    const int b     = blockIdx.x;   // 0..127
    const int chunk = blockIdx.y;   // 0..7
    const int t     = threadIdx.x;
    const int wave  = t >> 6;
    const int lane  = t & 63;

    float* alpha_out = out;                    // [B][N]
    float* c_out     = out + BB * NN;          // [B][D]
    float* npe_out   = c_out + BB * DD;        // [B][N]
    float* npee_out  = npe_out + BB * NN;      // [B][N]

    // q fragment: lane owns d = j*256 + lane*4 (+0..3), j = 0..7
    const float4* q4 = (const float4*)(q + (size_t)b * DD);
    float4 qv[8];
#pragma unroll
    for (int j = 0; j < 8; j++) qv[j] = q4[j * 64 + lane];

    float4 cacc[8];
#pragma unroll
    for (int j = 0; j < 8; j++) cacc[j] = make_float4(0.f, 0.f, 0.f, 0.f);

    const int n0 = chunk * 128 + wave * 32;

    for (int i = 0; i < 32; i++) {
        const int n = n0 + i;
        const float4* h4 = (const float4*)(h + ((size_t)b * NN + n) * DD);
        float4 hv[8];
#pragma unroll
        for (int j = 0; j < 8; j++) hv[j] = h4[j * 64 + lane];

        float dot = 0.f;
#pragma unroll
        for (int j = 0; j < 8; j++)
            dot += qv[j].x * hv[j].x + qv[j].y * hv[j].y +
                   qv[j].z * hv[j].z + qv[j].w * hv[j].w;
#pragma unroll
        for (int m = 1; m < 64; m <<= 1) dot += __shfl_xor(dot, m, 64);

        const float pev  = pe[b * NN + n];
        const float peev = pee[b * NN + n];
        const float ee   = __expf(dot);
        const float eet  = ee / pev;
        const float a    = eet / peev;
        if (lane == 0) {
            alpha_out[b * NN + n] = a;
            npe_out[b * NN + n]   = pev + ee;
            npee_out[b * NN + n]  = peev + eet;
        }
#pragma unroll
        for (int j = 0; j < 8; j++) {
            cacc[j].x += a * hv[j].x;
            cacc[j].y += a * hv[j].y;
            cacc[j].z += a * hv[j].z;
            cacc[j].w += a * hv[j].w;
        }
    }

    // combine 4 waves' partial c via LDS, one atomicAdd per d-element
    __shared__ float cl[4][DD];
#pragma unroll
    for (int j = 0; j < 8; j++)
        *(float4*)&cl[wave][j * 256 + lane * 4] = cacc[j];
    __syncthreads();
#pragma unroll
    for (int e = 0; e < 8; e++) {
        int d = e * 256 + t;
        float s = cl[0][d] + cl[1][d] + cl[2][d] + cl[3][d];
        atomicAdd(&c_out[(size_t)b * DD + d], s);
    }
}

extern "C" void kernel_launch(void* const* d_in, const int* in_sizes, int n_in,
                              void* d_out, int out_size, void* d_ws, size_t ws_size,
                              hipStream_t stream) {
    const float* ht  = (const float*)d_in[0];   // [B,D]
    const float* h   = (const float*)d_in[1];   // [B,N,D]
    const float* pe  = (const float*)d_in[2];   // [B,N]
    const float* pee = (const float*)d_in[3];   // [B,N]
    const float* W   = (const float*)d_in[4];   // [D,D]
    float* out = (float*)d_out;
    float* q   = (float*)d_ws;                  // [B,D] scratch

    // zero atomic targets (memset nodes are graph-capture safe)
    hipMemsetAsync(q, 0, (size_t)BB * DD * sizeof(float), stream);
    hipMemsetAsync(out + BB * NN, 0, (size_t)BB * DD * sizeof(float), stream);

    qgemm<<<dim3(16, 16), 256, 0, stream>>>(ht, W, q);
    fused<<<dim3(BB, 8), 256, 0, stream>>>(q, h, pe, pee, out);
}

// Round 2
// 256.644 us; speedup vs baseline: 1.4136x; 1.4136x over previous
//
#include <hip/hip_runtime.h>
#include <hip/hip_bf16.h>

#define BB 128
#define NN 1024
#define DD 2048

// ---- Kernel 1: q = h_t @ W_attn, k-split partials (no atomics on main path) ----
// grid (16 d-tiles, 2 b-tiles, 8 k-splits), block 256 = 16tx x 16ty.
// tile: d=128 (tx*8), b=64 (ty*4), k-range 256.
__global__ __launch_bounds__(256) void qgemm(const float* __restrict__ ht,
                                             const float* __restrict__ W,
                                             float* __restrict__ qdst,
                                             int partial) {
    const int d0 = blockIdx.x * 128;
    const int b0 = blockIdx.y * 64;
    const int ks = blockIdx.z;
    const int k0 = ks * 256;
    const int t  = threadIdx.x;
    const int tx = t & 15;
    const int ty = t >> 4;

    __shared__ float hs[64][33];    // [b][kk], pad: conflict-free scalar reads
    __shared__ float ws[32][132];   // [kk][d], 132 floats = 16B-aligned rows

    float acc[4][8];
#pragma unroll
    for (int i = 0; i < 4; i++)
#pragma unroll
        for (int j = 0; j < 8; j++) acc[i][j] = 0.f;

    for (int kc = 0; kc < 256; kc += 32) {
        __syncthreads();
#pragma unroll
        for (int i = 0; i < 8; i++) {          // hs: 64x32 = 2048 elems
            int idx = i * 256 + t;
            int c = idx & 31, r = idx >> 5;
            hs[r][c] = ht[(size_t)(b0 + r) * DD + k0 + kc + c];
        }
#pragma unroll
        for (int i = 0; i < 16; i++) {         // ws: 32x128 = 4096 elems
            int idx = i * 256 + t;
            int c = idx & 127, r = idx >> 7;
            ws[r][c] = W[(size_t)(k0 + kc + r) * DD + d0 + c];
        }
        __syncthreads();
#pragma unroll
        for (int kk = 0; kk < 32; kk++) {
            const float4* wr = (const float4*)&ws[kk][tx * 8];
            float4 w0 = wr[0], w1 = wr[1];
            float hv[4];
#pragma unroll
            for (int i = 0; i < 4; i++) hv[i] = hs[ty * 4 + i][kk];
#pragma unroll
            for (int i = 0; i < 4; i++) {
                acc[i][0] += hv[i] * w0.x; acc[i][1] += hv[i] * w0.y;
                acc[i][2] += hv[i] * w0.z; acc[i][3] += hv[i] * w0.w;
                acc[i][4] += hv[i] * w1.x; acc[i][5] += hv[i] * w1.y;
                acc[i][6] += hv[i] * w1.z; acc[i][7] += hv[i] * w1.w;
            }
        }
    }
    if (partial) {
        float* dst = qdst + (size_t)ks * BB * DD;
#pragma unroll
        for (int i = 0; i < 4; i++) {
            int b = b0 + ty * 4 + i;
            float4 v0 = make_float4(acc[i][0], acc[i][1], acc[i][2], acc[i][3]);
            float4 v1 = make_float4(acc[i][4], acc[i][5], acc[i][6], acc[i][7]);
            *(float4*)&dst[(size_t)b * DD + d0 + tx * 8]     = v0;
            *(float4*)&dst[(size_t)b * DD + d0 + tx * 8 + 4] = v1;
        }
    } else {
#pragma unroll
        for (int i = 0; i < 4; i++)
#pragma unroll
            for (int j = 0; j < 8; j++)
                atomicAdd(&qdst[(size_t)(b0 + ty * 4 + i) * DD + d0 + tx * 8 + j],
                          acc[i][j]);
    }
}

// ---- generic k-way partial reduce: out[i] = sum_s part[s*BB*DD + i] ----
__global__ __launch_bounds__(256) void reduceK(const float* __restrict__ part,
                                               float* __restrict__ out, int k) {
    int i = blockIdx.x * 256 + threadIdx.x;    // float4 index, BB*DD/4 total
    const float4* p4 = (const float4*)part;
    float4 a = p4[i];
    for (int s = 1; s < k; s++) {
        float4 v = p4[(size_t)s * (BB * DD / 4) + i];
        a.x += v.x; a.y += v.y; a.z += v.z; a.w += v.w;
    }
    ((float4*)out)[i] = a;
}

// ---- Kernel 2: fused scores + elementwise + context, 2 rows/iter ----
// grid (B, 8 n-chunks), block 256 = 4 waves, wave owns 32 rows (16 dual iters).
__global__ __launch_bounds__(256) void fused(const float* __restrict__ q,
                                             const float* __restrict__ h,
                                             const float* __restrict__ pe,
                                             const float* __restrict__ pee,
                                             float* __restrict__ out,
                                             float* __restrict__ cdst,
                                             int partial) {
    const int b     = blockIdx.x;
    const int chunk = blockIdx.y;
    const int t     = threadIdx.x;
    const int wave  = t >> 6;
    const int lane  = t & 63;

    float* alpha_out = out;                    // [B][N]
    float* c_out     = out + (size_t)BB * NN;  // [B][D]
    float* npe_out   = c_out + (size_t)BB * DD;
    float* npee_out  = npe_out + (size_t)BB * NN;

    const float4* q4 = (const float4*)(q + (size_t)b * DD);
    float4 qv[8];
#pragma unroll
    for (int j = 0; j < 8; j++) qv[j] = q4[j * 64 + lane];

    float4 cacc[8];
#pragma unroll
    for (int j = 0; j < 8; j++) cacc[j] = make_float4(0.f, 0.f, 0.f, 0.f);

    const int n0 = chunk * 128 + wave * 32;

    for (int i = 0; i < 16; i++) {
        const int r0 = n0 + 2 * i;
        const float4* h0 = (const float4*)(h + ((size_t)b * NN + r0) * DD);
        const float4* h1 = h0 + DD / 4;
        float4 hv0[8], hv1[8];
#pragma unroll
        for (int j = 0; j < 8; j++) hv0[j] = h0[j * 64 + lane];
#pragma unroll
        for (int j = 0; j < 8; j++) hv1[j] = h1[j * 64 + lane];

        float dot0 = 0.f, dot1 = 0.f;
#pragma unroll
        for (int j = 0; j < 8; j++) {
            dot0 += qv[j].x * hv0[j].x + qv[j].y * hv0[j].y +
                    qv[j].z * hv0[j].z + qv[j].w * hv0[j].w;
            dot1 += qv[j].x * hv1[j].x + qv[j].y * hv1[j].y +
                    qv[j].z * hv1[j].z + qv[j].w * hv1[j].w;
        }
        // dual-row reduce: fold halves, select, shared 5-step butterfly
        float t0 = dot0 + __shfl_xor(dot0, 32);
        float t1 = dot1 + __shfl_xor(dot1, 32);
        float u  = (lane < 32) ? t0 : t1;
#pragma unroll
        for (int m = 16; m >= 1; m >>= 1) u += __shfl_xor(u, m);
        // lanes<32 hold full dot(r0); lanes>=32 hold dot(r1)
        const int n = r0 + (lane >> 5);
        const float pev  = pe[(size_t)b * NN + n];
        const float peev = pee[(size_t)b * NN + n];
        const float ee   = __expf(u);
        const float eet  = ee * __builtin_amdgcn_rcpf(pev);
        const float a    = eet * __builtin_amdgcn_rcpf(peev);
        if ((lane & 31) == 0) {
            alpha_out[(size_t)b * NN + n] = a;
            npe_out[(size_t)b * NN + n]   = pev + ee;
            npee_out[(size_t)b * NN + n]  = peev + eet;
        }
        const float a0 = __shfl(a, 0);
        const float a1 = __shfl(a, 32);
#pragma unroll
        for (int j = 0; j < 8; j++) {
            cacc[j].x += a0 * hv0[j].x + a1 * hv1[j].x;
            cacc[j].y += a0 * hv0[j].y + a1 * hv1[j].y;
            cacc[j].z += a0 * hv0[j].z + a1 * hv1[j].z;
            cacc[j].w += a0 * hv0[j].w + a1 * hv1[j].w;
        }
    }

    __shared__ float cl[4][DD];
#pragma unroll
    for (int j = 0; j < 8; j++)
        *(float4*)&cl[wave][j * 256 + lane * 4] = cacc[j];
    __syncthreads();
#pragma unroll
    for (int e = 0; e < 8; e++) {
        int d = e * 256 + t;
        float s = cl[0][d] + cl[1][d] + cl[2][d] + cl[3][d];
        if (partial)
            cdst[((size_t)chunk * BB + b) * DD + d] = s;
        else
            atomicAdd(&c_out[(size_t)b * DD + d], s);
    }
}

extern "C" void kernel_launch(void* const* d_in, const int* in_sizes, int n_in,
                              void* d_out, int out_size, void* d_ws, size_t ws_size,
                              hipStream_t stream) {
    const float* ht  = (const float*)d_in[0];
    const float* h   = (const float*)d_in[1];
    const float* pe  = (const float*)d_in[2];
    const float* pee = (const float*)d_in[3];
    const float* W   = (const float*)d_in[4];
    float* out = (float*)d_out;
    float* ws  = (float*)d_ws;

    const size_t SLAB = (size_t)BB * DD;               // 256K floats = 1 MB
    const size_t need = (8 + 8 + 1) * SLAB * sizeof(float);

    if (ws_size >= need) {
        float* qpart = ws;                 // [8][B][D]
        float* cpart = ws + 8 * SLAB;      // [8][B][D]
        float* q     = ws + 16 * SLAB;     // [B][D]
        qgemm<<<dim3(16, 2, 8), 256, 0, stream>>>(ht, W, qpart, 1);
        reduceK<<<dim3(BB * DD / 4 / 256), 256, 0, stream>>>(qpart, q, 8);
        fused<<<dim3(BB, 8), 256, 0, stream>>>(q, h, pe, pee, out, cpart, 1);
        reduceK<<<dim3(BB * DD / 4 / 256), 256, 0, stream>>>(cpart, out + (size_t)BB * NN, 8);
    } else {
        float* q = ws;
        hipMemsetAsync(q, 0, SLAB * sizeof(float), stream);
        hipMemsetAsync(out + (size_t)BB * NN, 0, SLAB * sizeof(float), stream);
        qgemm<<<dim3(16, 2, 8), 256, 0, stream>>>(ht, W, q, 0);
        fused<<<dim3(BB, 8), 256, 0, stream>>>(q, h, pe, pee, out, nullptr, 0);
    }
}

// Round 3
// 245.341 us; speedup vs baseline: 1.4787x; 1.0461x over previous
//
#include <hip/hip_runtime.h>
#include <hip/hip_bf16.h>

#define BB 128
#define NN 1024
#define DD 2048
#define KS 8    // k-splits in qgemm
#define CH 4    // n-chunks in fused

// ---- Kernel 1: qpart[ks][B][D] partials of h_t @ W_attn (no atomics) ----
// grid (16 d-tiles, 2 b-tiles, KS k-splits), block 256 = 16tx x 16ty.
__global__ __launch_bounds__(256) void qgemm(const float* __restrict__ ht,
                                             const float* __restrict__ W,
                                             float* __restrict__ qdst,
                                             int partial) {
    const int d0 = blockIdx.x * 128;
    const int b0 = blockIdx.y * 64;
    const int ks = blockIdx.z;
    const int KRANGE = DD / KS;             // 256
    const int k0 = ks * KRANGE;
    const int t  = threadIdx.x;
    const int tx = t & 15;
    const int ty = t >> 4;

    __shared__ float hs[64][33];
    __shared__ float ws[32][132];

    float acc[4][8];
#pragma unroll
    for (int i = 0; i < 4; i++)
#pragma unroll
        for (int j = 0; j < 8; j++) acc[i][j] = 0.f;

    for (int kc = 0; kc < KRANGE; kc += 32) {
        __syncthreads();
#pragma unroll
        for (int i = 0; i < 8; i++) {
            int idx = i * 256 + t;
            int c = idx & 31, r = idx >> 5;
            hs[r][c] = ht[(size_t)(b0 + r) * DD + k0 + kc + c];
        }
#pragma unroll
        for (int i = 0; i < 16; i++) {
            int idx = i * 256 + t;
            int c = idx & 127, r = idx >> 7;
            ws[r][c] = W[(size_t)(k0 + kc + r) * DD + d0 + c];
        }
        __syncthreads();
#pragma unroll
        for (int kk = 0; kk < 32; kk++) {
            const float4* wr = (const float4*)&ws[kk][tx * 8];
            float4 w0 = wr[0], w1 = wr[1];
            float hv[4];
#pragma unroll
            for (int i = 0; i < 4; i++) hv[i] = hs[ty * 4 + i][kk];
#pragma unroll
            for (int i = 0; i < 4; i++) {
                acc[i][0] += hv[i] * w0.x; acc[i][1] += hv[i] * w0.y;
                acc[i][2] += hv[i] * w0.z; acc[i][3] += hv[i] * w0.w;
                acc[i][4] += hv[i] * w1.x; acc[i][5] += hv[i] * w1.y;
                acc[i][6] += hv[i] * w1.z; acc[i][7] += hv[i] * w1.w;
            }
        }
    }
    if (partial) {
        float* dst = qdst + (size_t)ks * BB * DD;
#pragma unroll
        for (int i = 0; i < 4; i++) {
            int b = b0 + ty * 4 + i;
            *(float4*)&dst[(size_t)b * DD + d0 + tx * 8] =
                make_float4(acc[i][0], acc[i][1], acc[i][2], acc[i][3]);
            *(float4*)&dst[(size_t)b * DD + d0 + tx * 8 + 4] =
                make_float4(acc[i][4], acc[i][5], acc[i][6], acc[i][7]);
        }
    } else {
#pragma unroll
        for (int i = 0; i < 4; i++)
#pragma unroll
            for (int j = 0; j < 8; j++)
                atomicAdd(&qdst[(size_t)(b0 + ty * 4 + i) * DD + d0 + tx * 8 + j],
                          acc[i][j]);
    }
}

// ---- Kernel 2: fused q-reduce + scores + elementwise + context ----
// grid (B, CH), block 256 = 4 waves; wave owns NN/CH/4 rows (dual-row iters).
template <int NS>
__global__ __launch_bounds__(256) void fused(const float* __restrict__ qpart,
                                             const float* __restrict__ h,
                                             const float* __restrict__ pe,
                                             const float* __restrict__ pee,
                                             float* __restrict__ out,
                                             float* __restrict__ cdst) {
    const int b     = blockIdx.x;
    const int chunk = blockIdx.y;
    const int t     = threadIdx.x;
    const int wave  = t >> 6;
    const int lane  = t & 63;

    float* alpha_out = out;                     // [B][N]
    float* c_out     = out + (size_t)BB * NN;   // [B][D]
    float* npe_out   = c_out + (size_t)BB * DD; // [B][N]
    float* npee_out  = npe_out + (size_t)BB * NN;

    __shared__ float qs[DD];                    // reduced q[b], 8 KB
    {
        const float4* qp4 = (const float4*)qpart;
        const size_t slab = (size_t)BB * DD / 4;
#pragma unroll
        for (int r = 0; r < 2; r++) {
            int f = r * 256 + t;
            float4 a = qp4[(size_t)b * (DD / 4) + f];
#pragma unroll
            for (int s = 1; s < NS; s++) {
                float4 v = qp4[(size_t)s * slab + (size_t)b * (DD / 4) + f];
                a.x += v.x; a.y += v.y; a.z += v.z; a.w += v.w;
            }
            *(float4*)&qs[f * 4] = a;
        }
    }
    __syncthreads();

    float4 qv[8];
#pragma unroll
    for (int j = 0; j < 8; j++) qv[j] = ((const float4*)qs)[j * 64 + lane];

    float4 cacc[8];
#pragma unroll
    for (int j = 0; j < 8; j++) cacc[j] = make_float4(0.f, 0.f, 0.f, 0.f);

    const int ROWS = NN / CH / 4;               // rows per wave (64)
    const int n0 = chunk * (NN / CH) + wave * ROWS;

    for (int i = 0; i < ROWS / 2; i++) {
        const int r0 = n0 + 2 * i;
        const float4* h0 = (const float4*)(h + ((size_t)b * NN + r0) * DD);
        const float4* h1 = h0 + DD / 4;
        float4 hv0[8], hv1[8];
#pragma unroll
        for (int j = 0; j < 8; j++) hv0[j] = h0[j * 64 + lane];
#pragma unroll
        for (int j = 0; j < 8; j++) hv1[j] = h1[j * 64 + lane];

        float dot0 = 0.f, dot1 = 0.f;
#pragma unroll
        for (int j = 0; j < 8; j++) {
            dot0 += qv[j].x * hv0[j].x + qv[j].y * hv0[j].y +
                    qv[j].z * hv0[j].z + qv[j].w * hv0[j].w;
            dot1 += qv[j].x * hv1[j].x + qv[j].y * hv1[j].y +
                    qv[j].z * hv1[j].z + qv[j].w * hv1[j].w;
        }
        float t0 = dot0 + __shfl_xor(dot0, 32);
        float t1 = dot1 + __shfl_xor(dot1, 32);
        float u  = (lane < 32) ? t0 : t1;
#pragma unroll
        for (int m = 16; m >= 1; m >>= 1) u += __shfl_xor(u, m);

        const int n = r0 + (lane >> 5);
        const float pev  = pe[(size_t)b * NN + n];
        const float peev = pee[(size_t)b * NN + n];
        const float ee   = __expf(u);
        const float eet  = ee * __builtin_amdgcn_rcpf(pev);
        const float a    = eet * __builtin_amdgcn_rcpf(peev);
        if ((lane & 31) == 0) {
            alpha_out[(size_t)b * NN + n] = a;
            npe_out[(size_t)b * NN + n]   = pev + ee;
            npee_out[(size_t)b * NN + n]  = peev + eet;
        }
        const float a0 = __shfl(a, 0);
        const float a1 = __shfl(a, 32);
#pragma unroll
        for (int j = 0; j < 8; j++) {
            cacc[j].x += a0 * hv0[j].x + a1 * hv1[j].x;
            cacc[j].y += a0 * hv0[j].y + a1 * hv1[j].y;
            cacc[j].z += a0 * hv0[j].z + a1 * hv1[j].z;
            cacc[j].w += a0 * hv0[j].w + a1 * hv1[j].w;
        }
    }

    __shared__ float cl[4][DD];                 // 32 KB
#pragma unroll
    for (int j = 0; j < 8; j++)
        *(float4*)&cl[wave][j * 256 + lane * 4] = cacc[j];
    __syncthreads();
#pragma unroll
    for (int e = 0; e < 8; e++) {
        int d = e * 256 + t;
        float s = cl[0][d] + cl[1][d] + cl[2][d] + cl[3][d];
        if (cdst)
            cdst[((size_t)chunk * BB + b) * DD + d] = s;
        else
            atomicAdd(&c_out[(size_t)b * DD + d], s);
    }
}

// ---- Kernel 3: c_out = sum over CH chunk-partials ----
__global__ __launch_bounds__(256) void reduceC(const float* __restrict__ part,
                                               float* __restrict__ c_out) {
    int i = blockIdx.x * 256 + threadIdx.x;     // float4 index
    const float4* p4 = (const float4*)part;
    float4 a = p4[i];
#pragma unroll
    for (int s = 1; s < CH; s++) {
        float4 v = p4[(size_t)s * (BB * DD / 4) + i];
        a.x += v.x; a.y += v.y; a.z += v.z; a.w += v.w;
    }
    ((float4*)c_out)[i] = a;
}

extern "C" void kernel_launch(void* const* d_in, const int* in_sizes, int n_in,
                              void* d_out, int out_size, void* d_ws, size_t ws_size,
                              hipStream_t stream) {
    const float* ht  = (const float*)d_in[0];
    const float* h   = (const float*)d_in[1];
    const float* pe  = (const float*)d_in[2];
    const float* pee = (const float*)d_in[3];
    const float* W   = (const float*)d_in[4];
    float* out = (float*)d_out;
    float* ws  = (float*)d_ws;

    const size_t SLAB = (size_t)BB * DD;        // 256K floats = 1 MB
    const size_t need = (KS + CH) * SLAB * sizeof(float);

    if (ws_size >= need) {
        float* qpart = ws;                      // [KS][B][D]
        float* cpart = ws + KS * SLAB;          // [CH][B][D]
        qgemm<<<dim3(16, 2, KS), 256, 0, stream>>>(ht, W, qpart, 1);
        fused<KS><<<dim3(BB, CH), 256, 0, stream>>>(qpart, h, pe, pee, out, cpart);
        reduceC<<<dim3(BB * DD / 4 / 256), 256, 0, stream>>>(cpart, out + SLAB / 2 * 0 + (size_t)BB * NN);
    } else {
        float* q = ws;                          // [1][B][D]
        hipMemsetAsync(q, 0, SLAB * sizeof(float), stream);
        hipMemsetAsync(out + (size_t)BB * NN, 0, SLAB * sizeof(float), stream);
        qgemm<<<dim3(16, 2, KS), 256, 0, stream>>>(ht, W, q, 0);
        fused<1><<<dim3(BB, CH), 256, 0, stream>>>(q, h, pe, pee, out, nullptr);
    }
}

// Round 4
// 213.239 us; speedup vs baseline: 1.7013x; 1.1505x over previous
//
#include <hip/hip_runtime.h>
#include <hip/hip_bf16.h>

#define BB 128
#define NN 1024
#define DD 2048
#define KS 8    // k-splits in qgemm
#define CH 4    // n-chunks in fused

typedef float v4f __attribute__((ext_vector_type(4)));

// ---- Kernel 1: qpart[ks][B][D] partials of h_t @ W_attn ----
// grid (16 d-tiles, 4 b-tiles, KS k-splits) = 512 blocks (2/CU), block 256.
// tile: d=128 (tx*8), b=32 (ty*2), k-range 256.
__global__ __launch_bounds__(256) void qgemm(const float* __restrict__ ht,
                                             const float* __restrict__ W,
                                             float* __restrict__ qdst,
                                             int partial) {
    const int d0 = blockIdx.x * 128;
    const int b0 = blockIdx.y * 32;
    const int ks = blockIdx.z;
    const int KRANGE = DD / KS;             // 256
    const int k0 = ks * KRANGE;
    const int t  = threadIdx.x;
    const int tx = t & 15;
    const int ty = t >> 4;

    __shared__ float hs[32][33];    // [b][kk]
    __shared__ float ws[32][132];   // [kk][d]

    float acc[2][8];
#pragma unroll
    for (int i = 0; i < 2; i++)
#pragma unroll
        for (int j = 0; j < 8; j++) acc[i][j] = 0.f;

    for (int kc = 0; kc < KRANGE; kc += 32) {
        __syncthreads();
#pragma unroll
        for (int i = 0; i < 4; i++) {          // hs: 32x32 = 1024 elems
            int idx = i * 256 + t;
            int c = idx & 31, r = idx >> 5;
            hs[r][c] = ht[(size_t)(b0 + r) * DD + k0 + kc + c];
        }
#pragma unroll
        for (int i = 0; i < 16; i++) {         // ws: 32x128 = 4096 elems
            int idx = i * 256 + t;
            int c = idx & 127, r = idx >> 7;
            ws[r][c] = W[(size_t)(k0 + kc + r) * DD + d0 + c];
        }
        __syncthreads();
#pragma unroll
        for (int kk = 0; kk < 32; kk++) {
            const float4* wr = (const float4*)&ws[kk][tx * 8];
            float4 w0 = wr[0], w1 = wr[1];
            float hv[2];
#pragma unroll
            for (int i = 0; i < 2; i++) hv[i] = hs[ty * 2 + i][kk];
#pragma unroll
            for (int i = 0; i < 2; i++) {
                acc[i][0] += hv[i] * w0.x; acc[i][1] += hv[i] * w0.y;
                acc[i][2] += hv[i] * w0.z; acc[i][3] += hv[i] * w0.w;
                acc[i][4] += hv[i] * w1.x; acc[i][5] += hv[i] * w1.y;
                acc[i][6] += hv[i] * w1.z; acc[i][7] += hv[i] * w1.w;
            }
        }
    }
    if (partial) {
        float* dst = qdst + (size_t)ks * BB * DD;
#pragma unroll
        for (int i = 0; i < 2; i++) {
            int b = b0 + ty * 2 + i;
            *(float4*)&dst[(size_t)b * DD + d0 + tx * 8] =
                make_float4(acc[i][0], acc[i][1], acc[i][2], acc[i][3]);
            *(float4*)&dst[(size_t)b * DD + d0 + tx * 8 + 4] =
                make_float4(acc[i][4], acc[i][5], acc[i][6], acc[i][7]);
        }
    } else {
#pragma unroll
        for (int i = 0; i < 2; i++)
#pragma unroll
            for (int j = 0; j < 8; j++)
                atomicAdd(&qdst[(size_t)(b0 + ty * 2 + i) * DD + d0 + tx * 8 + j],
                          acc[i][j]);
    }
}

// ---- Kernel 2: fused q-reduce + scores + elementwise + context ----
// grid (B, CH) = 512 blocks (2/CU), block 256 = 4 waves; wave owns 64 rows.
// h is streamed with nontemporal loads (read-once, keep L2 clean).
template <int NS>
__global__ __launch_bounds__(256) void fused(const float* __restrict__ qpart,
                                             const float* __restrict__ h,
                                             const float* __restrict__ pe,
                                             const float* __restrict__ pee,
                                             float* __restrict__ out,
                                             float* __restrict__ cdst) {
    const int b     = blockIdx.x;
    const int chunk = blockIdx.y;
    const int t     = threadIdx.x;
    const int wave  = t >> 6;
    const int lane  = t & 63;

    float* alpha_out = out;                     // [B][N]
    float* c_out     = out + (size_t)BB * NN;   // [B][D]
    float* npe_out   = c_out + (size_t)BB * DD; // [B][N]
    float* npee_out  = npe_out + (size_t)BB * NN;

    __shared__ float qs[DD];                    // reduced q[b], 8 KB
    {
        const float4* qp4 = (const float4*)qpart;
        const size_t slab = (size_t)BB * DD / 4;
#pragma unroll
        for (int r = 0; r < 2; r++) {
            int f = r * 256 + t;
            float4 a = qp4[(size_t)b * (DD / 4) + f];
#pragma unroll
            for (int s = 1; s < NS; s++) {
                float4 v = qp4[(size_t)s * slab + (size_t)b * (DD / 4) + f];
                a.x += v.x; a.y += v.y; a.z += v.z; a.w += v.w;
            }
            *(float4*)&qs[f * 4] = a;
        }
    }
    __syncthreads();

    v4f qv[8];
#pragma unroll
    for (int j = 0; j < 8; j++) qv[j] = ((const v4f*)qs)[j * 64 + lane];

    v4f cacc[8];
#pragma unroll
    for (int j = 0; j < 8; j++) cacc[j] = (v4f)0.f;

    const int ROWS = NN / CH / 4;               // rows per wave (64)
    const int n0 = chunk * (NN / CH) + wave * ROWS;

    for (int i = 0; i < ROWS / 2; i++) {
        const int r0 = n0 + 2 * i;
        const v4f* h0 = (const v4f*)(h + ((size_t)b * NN + r0) * DD);
        const v4f* h1 = h0 + DD / 4;
        v4f hv0[8], hv1[8];
#pragma unroll
        for (int j = 0; j < 8; j++) hv0[j] = __builtin_nontemporal_load(&h0[j * 64 + lane]);
#pragma unroll
        for (int j = 0; j < 8; j++) hv1[j] = __builtin_nontemporal_load(&h1[j * 64 + lane]);

        float dot0 = 0.f, dot1 = 0.f;
#pragma unroll
        for (int j = 0; j < 8; j++) {
            dot0 += qv[j][0] * hv0[j][0] + qv[j][1] * hv0[j][1] +
                    qv[j][2] * hv0[j][2] + qv[j][3] * hv0[j][3];
            dot1 += qv[j][0] * hv1[j][0] + qv[j][1] * hv1[j][1] +
                    qv[j][2] * hv1[j][2] + qv[j][3] * hv1[j][3];
        }
        float t0 = dot0 + __shfl_xor(dot0, 32);
        float t1 = dot1 + __shfl_xor(dot1, 32);
        float u  = (lane < 32) ? t0 : t1;
#pragma unroll
        for (int m = 16; m >= 1; m >>= 1) u += __shfl_xor(u, m);

        const int n = r0 + (lane >> 5);
        const float pev  = pe[(size_t)b * NN + n];
        const float peev = pee[(size_t)b * NN + n];
        const float ee   = __expf(u);
        const float eet  = ee * __builtin_amdgcn_rcpf(pev);
        const float a    = eet * __builtin_amdgcn_rcpf(peev);
        if ((lane & 31) == 0) {
            alpha_out[(size_t)b * NN + n] = a;
            npe_out[(size_t)b * NN + n]   = pev + ee;
            npee_out[(size_t)b * NN + n]  = peev + eet;
        }
        const float a0 = __shfl(a, 0);
        const float a1 = __shfl(a, 32);
#pragma unroll
        for (int j = 0; j < 8; j++)
            cacc[j] += a0 * hv0[j] + a1 * hv1[j];
    }

    __shared__ float cl[4][DD];                 // 32 KB
#pragma unroll
    for (int j = 0; j < 8; j++)
        *(v4f*)&cl[wave][j * 256 + lane * 4] = cacc[j];
    __syncthreads();
#pragma unroll
    for (int e = 0; e < 8; e++) {
        int d = e * 256 + t;
        float s = cl[0][d] + cl[1][d] + cl[2][d] + cl[3][d];
        if (cdst)
            cdst[((size_t)chunk * BB + b) * DD + d] = s;
        else
            atomicAdd(&c_out[(size_t)b * DD + d], s);
    }
}

// ---- Kernel 3: c_out = sum over CH chunk-partials ----
__global__ __launch_bounds__(256) void reduceC(const float* __restrict__ part,
                                               float* __restrict__ c_out) {
    int i = blockIdx.x * 256 + threadIdx.x;     // float4 index
    const float4* p4 = (const float4*)part;
    float4 a = p4[i];
#pragma unroll
    for (int s = 1; s < CH; s++) {
        float4 v = p4[(size_t)s * (BB * DD / 4) + i];
        a.x += v.x; a.y += v.y; a.z += v.z; a.w += v.w;
    }
    ((float4*)c_out)[i] = a;
}

extern "C" void kernel_launch(void* const* d_in, const int* in_sizes, int n_in,
                              void* d_out, int out_size, void* d_ws, size_t ws_size,
                              hipStream_t stream) {
    const float* ht  = (const float*)d_in[0];
    const float* h   = (const float*)d_in[1];
    const float* pe  = (const float*)d_in[2];
    const float* pee = (const float*)d_in[3];
    const float* W   = (const float*)d_in[4];
    float* out = (float*)d_out;
    float* ws  = (float*)d_ws;

    const size_t SLAB = (size_t)BB * DD;        // 256K floats = 1 MB
    const size_t need = (KS + CH) * SLAB * sizeof(float);

    if (ws_size >= need) {
        float* qpart = ws;                      // [KS][B][D]
        float* cpart = ws + KS * SLAB;          // [CH][B][D]
        qgemm<<<dim3(16, 4, KS), 256, 0, stream>>>(ht, W, qpart, 1);
        fused<KS><<<dim3(BB, CH), 256, 0, stream>>>(qpart, h, pe, pee, out, cpart);
        reduceC<<<dim3(BB * DD / 4 / 256), 256, 0, stream>>>(cpart, out + (size_t)BB * NN);
    } else {
        float* q = ws;                          // [1][B][D]
        hipMemsetAsync(q, 0, SLAB * sizeof(float), stream);
        hipMemsetAsync(out + (size_t)BB * NN, 0, SLAB * sizeof(float), stream);
        qgemm<<<dim3(16, 4, KS), 256, 0, stream>>>(ht, W, q, 0);
        fused<1><<<dim3(BB, CH), 256, 0, stream>>>(q, h, pe, pee, out, nullptr);
    }
}

// Round 5
// 208.233 us; speedup vs baseline: 1.7422x; 1.0240x over previous
//
#include <hip/hip_runtime.h>
#include <hip/hip_bf16.h>

#define BB 128
#define NN 1024
#define DD 2048
#define KS 16   // k-splits in qgemm
#define CH 4    // n-chunks in fused

typedef float v4f __attribute__((ext_vector_type(4)));

// ---- Kernel 1: qpart[ks][B][D] partials of h_t @ W_attn ----
// grid (16 d-tiles, 2 b-tiles, KS k-splits) = 512 blocks (2/CU), block 256.
// tile: d=128 (tx*8), b=64 (ty*4), k-range 128. 32 FMA per 6 LDS instr.
__global__ __launch_bounds__(256) void qgemm(const float* __restrict__ ht,
                                             const float* __restrict__ W,
                                             float* __restrict__ qdst,
                                             int partial) {
    const int d0 = blockIdx.x * 128;
    const int b0 = blockIdx.y * 64;
    const int ks = blockIdx.z;
    const int KRANGE = DD / KS;             // 128
    const int k0 = ks * KRANGE;
    const int t  = threadIdx.x;
    const int tx = t & 15;
    const int ty = t >> 4;

    __shared__ float hs[64][33];    // [b][kk] (broadcast reads: conflict-free)
    __shared__ float ws[32][132];   // [kk][d] (16B-aligned rows)

    float acc[4][8];
#pragma unroll
    for (int i = 0; i < 4; i++)
#pragma unroll
        for (int j = 0; j < 8; j++) acc[i][j] = 0.f;

    for (int kc = 0; kc < KRANGE; kc += 32) {
        __syncthreads();
#pragma unroll
        for (int i = 0; i < 8; i++) {          // hs: 64x32 = 2048 elems
            int idx = i * 256 + t;
            int c = idx & 31, r = idx >> 5;
            hs[r][c] = ht[(size_t)(b0 + r) * DD + k0 + kc + c];
        }
#pragma unroll
        for (int i = 0; i < 16; i++) {         // ws: 32x128 = 4096 elems
            int idx = i * 256 + t;
            int c = idx & 127, r = idx >> 7;
            ws[r][c] = W[(size_t)(k0 + kc + r) * DD + d0 + c];
        }
        __syncthreads();
#pragma unroll
        for (int kk = 0; kk < 32; kk++) {
            const float4* wr = (const float4*)&ws[kk][tx * 8];
            float4 w0 = wr[0], w1 = wr[1];
            float hv[4];
#pragma unroll
            for (int i = 0; i < 4; i++) hv[i] = hs[ty * 4 + i][kk];
#pragma unroll
            for (int i = 0; i < 4; i++) {
                acc[i][0] += hv[i] * w0.x; acc[i][1] += hv[i] * w0.y;
                acc[i][2] += hv[i] * w0.z; acc[i][3] += hv[i] * w0.w;
                acc[i][4] += hv[i] * w1.x; acc[i][5] += hv[i] * w1.y;
                acc[i][6] += hv[i] * w1.z; acc[i][7] += hv[i] * w1.w;
            }
        }
    }
    if (partial) {
        float* dst = qdst + (size_t)ks * BB * DD;
#pragma unroll
        for (int i = 0; i < 4; i++) {
            int b = b0 + ty * 4 + i;
            *(float4*)&dst[(size_t)b * DD + d0 + tx * 8] =
                make_float4(acc[i][0], acc[i][1], acc[i][2], acc[i][3]);
            *(float4*)&dst[(size_t)b * DD + d0 + tx * 8 + 4] =
                make_float4(acc[i][4], acc[i][5], acc[i][6], acc[i][7]);
        }
    } else {
#pragma unroll
        for (int i = 0; i < 4; i++)
#pragma unroll
            for (int j = 0; j < 8; j++)
                atomicAdd(&qdst[(size_t)(b0 + ty * 4 + i) * DD + d0 + tx * 8 + j],
                          acc[i][j]);
    }
}

// ---- Kernel 2: fused q-reduce + scores + elementwise + context ----
// grid (B, CH) = 512 blocks (2/CU), block 256 = 4 waves; wave owns 64 rows.
// h is streamed with nontemporal loads (read-once, keep L2 clean).
template <int NS>
__global__ __launch_bounds__(256) void fused(const float* __restrict__ qpart,
                                             const float* __restrict__ h,
                                             const float* __restrict__ pe,
                                             const float* __restrict__ pee,
                                             float* __restrict__ out,
                                             float* __restrict__ cdst) {
    const int b     = blockIdx.x;
    const int chunk = blockIdx.y;
    const int t     = threadIdx.x;
    const int wave  = t >> 6;
    const int lane  = t & 63;

    float* alpha_out = out;                     // [B][N]
    float* c_out     = out + (size_t)BB * NN;   // [B][D]
    float* npe_out   = c_out + (size_t)BB * DD; // [B][N]
    float* npee_out  = npe_out + (size_t)BB * NN;

    __shared__ float qs[DD];                    // reduced q[b], 8 KB
    {
        const float4* qp4 = (const float4*)qpart;
        const size_t slab = (size_t)BB * DD / 4;
#pragma unroll
        for (int r = 0; r < 2; r++) {
            int f = r * 256 + t;
            float4 a = qp4[(size_t)b * (DD / 4) + f];
#pragma unroll
            for (int s = 1; s < NS; s++) {
                float4 v = qp4[(size_t)s * slab + (size_t)b * (DD / 4) + f];
                a.x += v.x; a.y += v.y; a.z += v.z; a.w += v.w;
            }
            *(float4*)&qs[f * 4] = a;
        }
    }
    __syncthreads();

    v4f qv[8];
#pragma unroll
    for (int j = 0; j < 8; j++) qv[j] = ((const v4f*)qs)[j * 64 + lane];

    v4f cacc[8];
#pragma unroll
    for (int j = 0; j < 8; j++) cacc[j] = (v4f)0.f;

    const int ROWS = NN / CH / 4;               // rows per wave (64)
    const int n0 = chunk * (NN / CH) + wave * ROWS;

    for (int i = 0; i < ROWS / 2; i++) {
        const int r0 = n0 + 2 * i;
        const v4f* h0 = (const v4f*)(h + ((size_t)b * NN + r0) * DD);
        const v4f* h1 = h0 + DD / 4;
        v4f hv0[8], hv1[8];
#pragma unroll
        for (int j = 0; j < 8; j++) hv0[j] = __builtin_nontemporal_load(&h0[j * 64 + lane]);
#pragma unroll
        for (int j = 0; j < 8; j++) hv1[j] = __builtin_nontemporal_load(&h1[j * 64 + lane]);

        float dot0 = 0.f, dot1 = 0.f;
#pragma unroll
        for (int j = 0; j < 8; j++) {
            dot0 += qv[j][0] * hv0[j][0] + qv[j][1] * hv0[j][1] +
                    qv[j][2] * hv0[j][2] + qv[j][3] * hv0[j][3];
            dot1 += qv[j][0] * hv1[j][0] + qv[j][1] * hv1[j][1] +
                    qv[j][2] * hv1[j][2] + qv[j][3] * hv1[j][3];
        }
        float t0 = dot0 + __shfl_xor(dot0, 32);
        float t1 = dot1 + __shfl_xor(dot1, 32);
        float u  = (lane < 32) ? t0 : t1;
#pragma unroll
        for (int m = 16; m >= 1; m >>= 1) u += __shfl_xor(u, m);

        const int n = r0 + (lane >> 5);
        const float pev  = pe[(size_t)b * NN + n];
        const float peev = pee[(size_t)b * NN + n];
        const float ee   = __expf(u);
        const float eet  = ee * __builtin_amdgcn_rcpf(pev);
        const float a    = eet * __builtin_amdgcn_rcpf(peev);
        if ((lane & 31) == 0) {
            alpha_out[(size_t)b * NN + n] = a;
            npe_out[(size_t)b * NN + n]   = pev + ee;
            npee_out[(size_t)b * NN + n]  = peev + eet;
        }
        const float a0 = __shfl(a, 0);
        const float a1 = __shfl(a, 32);
#pragma unroll
        for (int j = 0; j < 8; j++)
            cacc[j] += a0 * hv0[j] + a1 * hv1[j];
    }

    __shared__ float cl[4][DD];                 // 32 KB
#pragma unroll
    for (int j = 0; j < 8; j++)
        *(v4f*)&cl[wave][j * 256 + lane * 4] = cacc[j];
    __syncthreads();
#pragma unroll
    for (int e = 0; e < 8; e++) {
        int d = e * 256 + t;
        float s = cl[0][d] + cl[1][d] + cl[2][d] + cl[3][d];
        if (cdst)
            cdst[((size_t)chunk * BB + b) * DD + d] = s;
        else
            atomicAdd(&c_out[(size_t)b * DD + d], s);
    }
}

// ---- Kernel 3: c_out = sum over CH chunk-partials ----
__global__ __launch_bounds__(256) void reduceC(const float* __restrict__ part,
                                               float* __restrict__ c_out) {
    int i = blockIdx.x * 256 + threadIdx.x;     // float4 index
    const float4* p4 = (const float4*)part;
    float4 a = p4[i];
#pragma unroll
    for (int s = 1; s < CH; s++) {
        float4 v = p4[(size_t)s * (BB * DD / 4) + i];
        a.x += v.x; a.y += v.y; a.z += v.z; a.w += v.w;
    }
    ((float4*)c_out)[i] = a;
}

extern "C" void kernel_launch(void* const* d_in, const int* in_sizes, int n_in,
                              void* d_out, int out_size, void* d_ws, size_t ws_size,
                              hipStream_t stream) {
    const float* ht  = (const float*)d_in[0];
    const float* h   = (const float*)d_in[1];
    const float* pe  = (const float*)d_in[2];
    const float* pee = (const float*)d_in[3];
    const float* W   = (const float*)d_in[4];
    float* out = (float*)d_out;
    float* ws  = (float*)d_ws;

    const size_t SLAB = (size_t)BB * DD;        // 256K floats = 1 MB
    const size_t need = (KS + CH) * SLAB * sizeof(float);

    if (ws_size >= need) {
        float* qpart = ws;                      // [KS][B][D]
        float* cpart = ws + KS * SLAB;          // [CH][B][D]
        qgemm<<<dim3(16, 2, KS), 256, 0, stream>>>(ht, W, qpart, 1);
        fused<KS><<<dim3(BB, CH), 256, 0, stream>>>(qpart, h, pe, pee, out, cpart);
        reduceC<<<dim3(BB * DD / 4 / 256), 256, 0, stream>>>(cpart, out + (size_t)BB * NN);
    } else {
        float* q = ws;                          // [1][B][D]
        hipMemsetAsync(q, 0, SLAB * sizeof(float), stream);
        hipMemsetAsync(out + (size_t)BB * NN, 0, SLAB * sizeof(float), stream);
        qgemm<<<dim3(16, 2, KS), 256, 0, stream>>>(ht, W, q, 0);
        fused<1><<<dim3(BB, CH), 256, 0, stream>>>(q, h, pe, pee, out, nullptr);
    }
}

// Round 6
// 200.830 us; speedup vs baseline: 1.8064x; 1.0369x over previous
//
#include <hip/hip_runtime.h>
#include <hip/hip_bf16.h>

#define BB 128
#define NN 1024
#define DD 2048
#define KS 16   // k-splits in qgemm
#define CH 8    // n-chunks in fused

typedef float v4f __attribute__((ext_vector_type(4)));

// ---- Kernel 1: qpart[ks][B][D] partials of h_t @ W_attn ----
// grid (16 d-tiles, 2 b-tiles, KS k-splits) = 512 blocks (2/CU), block 256.
// tile: d=128 (tx*8), b=64 (ty*4), k-range 128. 32 FMA per 6 LDS instr.
__global__ __launch_bounds__(256) void qgemm(const float* __restrict__ ht,
                                             const float* __restrict__ W,
                                             float* __restrict__ qdst,
                                             int partial) {
    const int d0 = blockIdx.x * 128;
    const int b0 = blockIdx.y * 64;
    const int ks = blockIdx.z;
    const int KRANGE = DD / KS;             // 128
    const int k0 = ks * KRANGE;
    const int t  = threadIdx.x;
    const int tx = t & 15;
    const int ty = t >> 4;

    __shared__ float hs[64][33];    // [b][kk] (broadcast reads: conflict-free)
    __shared__ float ws[32][132];   // [kk][d] (16B-aligned rows)

    float acc[4][8];
#pragma unroll
    for (int i = 0; i < 4; i++)
#pragma unroll
        for (int j = 0; j < 8; j++) acc[i][j] = 0.f;

    for (int kc = 0; kc < KRANGE; kc += 32) {
        __syncthreads();
#pragma unroll
        for (int i = 0; i < 8; i++) {          // hs: 64x32 = 2048 elems
            int idx = i * 256 + t;
            int c = idx & 31, r = idx >> 5;
            hs[r][c] = ht[(size_t)(b0 + r) * DD + k0 + kc + c];
        }
#pragma unroll
        for (int i = 0; i < 16; i++) {         // ws: 32x128 = 4096 elems
            int idx = i * 256 + t;
            int c = idx & 127, r = idx >> 7;
            ws[r][c] = W[(size_t)(k0 + kc + r) * DD + d0 + c];
        }
        __syncthreads();
#pragma unroll
        for (int kk = 0; kk < 32; kk++) {
            const float4* wr = (const float4*)&ws[kk][tx * 8];
            float4 w0 = wr[0], w1 = wr[1];
            float hv[4];
#pragma unroll
            for (int i = 0; i < 4; i++) hv[i] = hs[ty * 4 + i][kk];
#pragma unroll
            for (int i = 0; i < 4; i++) {
                acc[i][0] += hv[i] * w0.x; acc[i][1] += hv[i] * w0.y;
                acc[i][2] += hv[i] * w0.z; acc[i][3] += hv[i] * w0.w;
                acc[i][4] += hv[i] * w1.x; acc[i][5] += hv[i] * w1.y;
                acc[i][6] += hv[i] * w1.z; acc[i][7] += hv[i] * w1.w;
            }
        }
    }
    if (partial) {
        float* dst = qdst + (size_t)ks * BB * DD;
#pragma unroll
        for (int i = 0; i < 4; i++) {
            int b = b0 + ty * 4 + i;
            *(float4*)&dst[(size_t)b * DD + d0 + tx * 8] =
                make_float4(acc[i][0], acc[i][1], acc[i][2], acc[i][3]);
            *(float4*)&dst[(size_t)b * DD + d0 + tx * 8 + 4] =
                make_float4(acc[i][4], acc[i][5], acc[i][6], acc[i][7]);
        }
    } else {
#pragma unroll
        for (int i = 0; i < 4; i++)
#pragma unroll
            for (int j = 0; j < 8; j++)
                atomicAdd(&qdst[(size_t)(b0 + ty * 4 + i) * DD + d0 + tx * 8 + j],
                          acc[i][j]);
    }
}

// ---- Kernel 2: fused q-reduce + scores + elementwise + context ----
// grid (B, CH) = 1024 blocks, block 256 = 4 waves; wave owns 32 rows,
// processed 4 rows/iteration: one exp + two rcp per 4 rows (quadrant trick).
// h is streamed with nontemporal loads (read-once, keep L2 clean).
template <int NS>
__global__ __launch_bounds__(256) void fused(const float* __restrict__ qpart,
                                             const float* __restrict__ h,
                                             const float* __restrict__ pe,
                                             const float* __restrict__ pee,
                                             float* __restrict__ out,
                                             float* __restrict__ cdst) {
    const int b     = blockIdx.x;
    const int chunk = blockIdx.y;
    const int t     = threadIdx.x;
    const int wave  = t >> 6;
    const int lane  = t & 63;

    float* alpha_out = out;                     // [B][N]
    float* c_out     = out + (size_t)BB * NN;   // [B][D]
    float* npe_out   = c_out + (size_t)BB * DD; // [B][N]
    float* npee_out  = npe_out + (size_t)BB * NN;

    __shared__ float qs[DD];                    // reduced q[b], 8 KB
    {
        const float4* qp4 = (const float4*)qpart;
        const size_t slab = (size_t)BB * DD / 4;
#pragma unroll
        for (int r = 0; r < 2; r++) {
            int f = r * 256 + t;
            float4 a = qp4[(size_t)b * (DD / 4) + f];
#pragma unroll
            for (int s = 1; s < NS; s++) {
                float4 v = qp4[(size_t)s * slab + (size_t)b * (DD / 4) + f];
                a.x += v.x; a.y += v.y; a.z += v.z; a.w += v.w;
            }
            *(float4*)&qs[f * 4] = a;
        }
    }
    __syncthreads();

    v4f qv[8];
#pragma unroll
    for (int j = 0; j < 8; j++) qv[j] = ((const v4f*)qs)[j * 64 + lane];

    v4f cacc[8];
#pragma unroll
    for (int j = 0; j < 8; j++) cacc[j] = (v4f)0.f;

    const int ROWS = NN / CH / 4;               // rows per wave (32)
    const int n0 = chunk * (NN / CH) + wave * ROWS;
    const int quad = lane >> 4;                 // 0..3

    for (int i = 0; i < ROWS / 4; i++) {
        const int r0 = n0 + 4 * i;
        const v4f* hp = (const v4f*)(h + ((size_t)b * NN + r0) * DD);
        v4f hv0[8], hv1[8], hv2[8], hv3[8];
#pragma unroll
        for (int j = 0; j < 8; j++) hv0[j] = __builtin_nontemporal_load(&hp[j * 64 + lane]);
#pragma unroll
        for (int j = 0; j < 8; j++) hv1[j] = __builtin_nontemporal_load(&hp[512 + j * 64 + lane]);
#pragma unroll
        for (int j = 0; j < 8; j++) hv2[j] = __builtin_nontemporal_load(&hp[1024 + j * 64 + lane]);
#pragma unroll
        for (int j = 0; j < 8; j++) hv3[j] = __builtin_nontemporal_load(&hp[1536 + j * 64 + lane]);

        float d0 = 0.f, d1 = 0.f, d2 = 0.f, d3 = 0.f;
#pragma unroll
        for (int j = 0; j < 8; j++) {
            d0 += qv[j][0] * hv0[j][0] + qv[j][1] * hv0[j][1] +
                  qv[j][2] * hv0[j][2] + qv[j][3] * hv0[j][3];
            d1 += qv[j][0] * hv1[j][0] + qv[j][1] * hv1[j][1] +
                  qv[j][2] * hv1[j][2] + qv[j][3] * hv1[j][3];
            d2 += qv[j][0] * hv2[j][0] + qv[j][1] * hv2[j][1] +
                  qv[j][2] * hv2[j][2] + qv[j][3] * hv2[j][3];
            d3 += qv[j][0] * hv3[j][0] + qv[j][1] * hv3[j][1] +
                  qv[j][2] * hv3[j][2] + qv[j][3] * hv3[j][3];
        }
        // fold each row over lane bits 5,4 -> 16 partials replicated x4
        float f0 = d0 + __shfl_xor(d0, 32); f0 += __shfl_xor(f0, 16);
        float f1 = d1 + __shfl_xor(d1, 32); f1 += __shfl_xor(f1, 16);
        float f2 = d2 + __shfl_xor(d2, 32); f2 += __shfl_xor(f2, 16);
        float f3 = d3 + __shfl_xor(d3, 32); f3 += __shfl_xor(f3, 16);
        // quadrant q reduces row q
        float u = (quad == 0) ? f0 : (quad == 1) ? f1 : (quad == 2) ? f2 : f3;
#pragma unroll
        for (int m = 8; m >= 1; m >>= 1) u += __shfl_xor(u, m);

        const int n = r0 + quad;
        const float pev  = pe[(size_t)b * NN + n];
        const float peev = pee[(size_t)b * NN + n];
        const float ee   = __expf(u);
        const float eet  = ee * __builtin_amdgcn_rcpf(pev);
        const float a    = eet * __builtin_amdgcn_rcpf(peev);
        if ((lane & 15) == 0) {
            alpha_out[(size_t)b * NN + n] = a;
            npe_out[(size_t)b * NN + n]   = pev + ee;
            npee_out[(size_t)b * NN + n]  = peev + eet;
        }
        const float a0 = __shfl(a, 0);
        const float a1 = __shfl(a, 16);
        const float a2 = __shfl(a, 32);
        const float a3 = __shfl(a, 48);
#pragma unroll
        for (int j = 0; j < 8; j++)
            cacc[j] += a0 * hv0[j] + a1 * hv1[j] + a2 * hv2[j] + a3 * hv3[j];
    }

    __shared__ float cl[4][DD];                 // 32 KB
#pragma unroll
    for (int j = 0; j < 8; j++)
        *(v4f*)&cl[wave][j * 256 + lane * 4] = cacc[j];
    __syncthreads();
#pragma unroll
    for (int e = 0; e < 8; e++) {
        int d = e * 256 + t;
        float s = cl[0][d] + cl[1][d] + cl[2][d] + cl[3][d];
        if (cdst)
            cdst[((size_t)chunk * BB + b) * DD + d] = s;
        else
            atomicAdd(&c_out[(size_t)b * DD + d], s);
    }
}

// ---- Kernel 3: c_out = sum over CH chunk-partials ----
__global__ __launch_bounds__(256) void reduceC(const float* __restrict__ part,
                                               float* __restrict__ c_out) {
    int i = blockIdx.x * 256 + threadIdx.x;     // float4 index
    const float4* p4 = (const float4*)part;
    float4 a = p4[i];
#pragma unroll
    for (int s = 1; s < CH; s++) {
        float4 v = p4[(size_t)s * (BB * DD / 4) + i];
        a.x += v.x; a.y += v.y; a.z += v.z; a.w += v.w;
    }
    ((float4*)c_out)[i] = a;
}

extern "C" void kernel_launch(void* const* d_in, const int* in_sizes, int n_in,
                              void* d_out, int out_size, void* d_ws, size_t ws_size,
                              hipStream_t stream) {
    const float* ht  = (const float*)d_in[0];
    const float* h   = (const float*)d_in[1];
    const float* pe  = (const float*)d_in[2];
    const float* pee = (const float*)d_in[3];
    const float* W   = (const float*)d_in[4];
    float* out = (float*)d_out;
    float* ws  = (float*)d_ws;

    const size_t SLAB = (size_t)BB * DD;        // 256K floats = 1 MB
    const size_t need = (KS + CH) * SLAB * sizeof(float);

    if (ws_size >= need) {
        float* qpart = ws;                      // [KS][B][D]
        float* cpart = ws + KS * SLAB;          // [CH][B][D]
        qgemm<<<dim3(16, 2, KS), 256, 0, stream>>>(ht, W, qpart, 1);
        fused<KS><<<dim3(BB, CH), 256, 0, stream>>>(qpart, h, pe, pee, out, cpart);
        reduceC<<<dim3(BB * DD / 4 / 256), 256, 0, stream>>>(cpart, out + (size_t)BB * NN);
    } else {
        float* q = ws;                          // [1][B][D]
        hipMemsetAsync(q, 0, SLAB * sizeof(float), stream);
        hipMemsetAsync(out + (size_t)BB * NN, 0, SLAB * sizeof(float), stream);
        qgemm<<<dim3(16, 2, KS), 256, 0, stream>>>(ht, W, q, 0);
        fused<1><<<dim3(BB, CH), 256, 0, stream>>>(q, h, pe, pee, out, nullptr);
    }
}